// Round 1
// baseline (198.025 us; speedup 1.0000x reference)
//
#include <hip/hip_runtime.h>

#define TT 2048
#define EMB 1024
#define NH 16
#define HD 64
#define CTX 250

typedef __attribute__((ext_vector_type(4))) float f32x4;
typedef __attribute__((ext_vector_type(8))) short s16x8;
typedef __attribute__((ext_vector_type(4))) short s16x4;

__device__ __forceinline__ short f2bf(float f) {
  union { float f; unsigned u; } v; v.f = f;
  unsigned r = v.u + 0x7fffu + ((v.u >> 16) & 1u);
  return (short)(r >> 16);
}
__device__ __forceinline__ float bf2f(unsigned short u) {
  union { unsigned u; float f; } v; v.u = ((unsigned)u) << 16;
  return v.f;
}

__global__ void cvt_bf16x4(const float* __restrict__ in, short* __restrict__ out, int n4) {
  int i = blockIdx.x * blockDim.x + threadIdx.x;
  if (i >= n4) return;
  float4 v = reinterpret_cast<const float4*>(in)[i];
  s16x4 o; o[0] = f2bf(v.x); o[1] = f2bf(v.y); o[2] = f2bf(v.z); o[3] = f2bf(v.w);
  *reinterpret_cast<s16x4*>(out + i * 4) = o;
}

// C[M][N] = A[M][K] * W[N][K]^T  (bf16 inputs, MFMA 16x16x32, f32 accum)
// block = 256 thr = 4 waves (2x2), tile 128x128, each wave 64x64.
template<bool BF16OUT>
__global__ __launch_bounds__(256) void gemm_bt(const short* __restrict__ A,
                                               const short* __restrict__ W,
                                               void* __restrict__ Cv, int N, int K) {
  int lane = threadIdx.x & 63;
  int wid = threadIdx.x >> 6;
  int lr = lane & 15, lg = lane >> 4;
  int rbase = blockIdx.y * 128 + (wid >> 1) * 64;
  int cbase = blockIdx.x * 128 + (wid & 1) * 64;
  f32x4 acc[4][4] = {};
  const short* Ap = A + (rbase + lr) * K + lg * 8;
  const short* Wp = W + (cbase + lr) * K + lg * 8;
  for (int kk = 0; kk < K; kk += 32) {
    s16x8 a[4], b[4];
#pragma unroll
    for (int m = 0; m < 4; m++) a[m] = *reinterpret_cast<const s16x8*>(Ap + m * 16 * K + kk);
#pragma unroll
    for (int n = 0; n < 4; n++) b[n] = *reinterpret_cast<const s16x8*>(Wp + n * 16 * K + kk);
#pragma unroll
    for (int m = 0; m < 4; m++)
#pragma unroll
      for (int n = 0; n < 4; n++)
        acc[m][n] = __builtin_amdgcn_mfma_f32_16x16x32_bf16(a[m], b[n], acc[m][n], 0, 0, 0);
  }
#pragma unroll
  for (int m = 0; m < 4; m++)
#pragma unroll
    for (int n = 0; n < 4; n++)
#pragma unroll
      for (int r = 0; r < 4; r++) {
        int row = rbase + m * 16 + lg * 4 + r;
        int col = cbase + n * 16 + lr;
        float val = acc[m][n][r];
        if constexpr (BF16OUT) ((short*)Cv)[row * N + col] = f2bf(val);
        else                   ((float*)Cv)[row * N + col] = val;
      }
}

// proj (bf16, [B][T][3][H][D]) -> RoPE -> Qb/Kb/Vb (bf16, [B][H][T][D])
__global__ void rope_kernel(const short* __restrict__ proj, short* __restrict__ Qb,
                            short* __restrict__ Kb, short* __restrict__ Vb) {
  int idx = blockIdx.x * blockDim.x + threadIdx.x;  // B*H*T*32 = 2097152
  int i = idx & 31;
  int t = (idx >> 5) & (TT - 1);
  int h = (idx >> 16) & (NH - 1);
  int b = idx >> 20;
  int pbase = (b * TT + t) * 3 * EMB + h * HD + 2 * i;
  unsigned q01 = *reinterpret_cast<const unsigned*>(proj + pbase);
  unsigned k01 = *reinterpret_cast<const unsigned*>(proj + pbase + EMB);
  unsigned v01 = *reinterpret_cast<const unsigned*>(proj + pbase + 2 * EMB);
  float qa = bf2f((unsigned short)(q01 & 0xffff)), qb_ = bf2f((unsigned short)(q01 >> 16));
  float ka = bf2f((unsigned short)(k01 & 0xffff)), kb_ = bf2f((unsigned short)(k01 >> 16));
  float freq = __expf(-(float)i * 0.2878231366f);  // ln(10000)/32
  float ang = (float)t * freq;
  float s, c;
  sincosf(ang, &s, &c);
  int obase = ((b * NH + h) * TT + t) * HD + 2 * i;
  unsigned qo = ((unsigned)(unsigned short)f2bf(qa * s + qb_ * c) << 16) |
                (unsigned short)f2bf(qa * c - qb_ * s);
  unsigned ko = ((unsigned)(unsigned short)f2bf(ka * s + kb_ * c) << 16) |
                (unsigned short)f2bf(ka * c - kb_ * s);
  *reinterpret_cast<unsigned*>(Qb + obase) = qo;
  *reinterpret_cast<unsigned*>(Kb + obase) = ko;
  *reinterpret_cast<unsigned*>(Vb + obase) = v01;
}

// one wave per (bh, 16-query-row tile). Flash-style over 32-key tiles.
__global__ __launch_bounds__(64) void attn_kernel(const short* __restrict__ Qb,
                                                  const short* __restrict__ Kb,
                                                  const short* __restrict__ Vb,
                                                  short* __restrict__ Xout) {
  const float NEG = -3.0e38f;
  int lane = threadIdx.x;
  int lr = lane & 15, lg = lane >> 4;
  int t0 = blockIdx.x * 16;
  int bh = blockIdx.y;
  int b = bh >> 4, h = bh & 15;
  const short* Qp = Qb + bh * TT * HD;
  const short* Kp = Kb + bh * TT * HD;
  const short* Vp = Vb + bh * TT * HD;
  s16x8 qf[2];
#pragma unroll
  for (int d2 = 0; d2 < 2; d2++)
    qf[d2] = *reinterpret_cast<const s16x8*>(Qp + (t0 + lr) * HD + d2 * 32 + lg * 8);
  f32x4 of[4] = {};
  float m_run[4], l_run[4];
#pragma unroll
  for (int r = 0; r < 4; r++) { m_run[r] = NEG; l_run[r] = 0.0f; }
  __shared__ __align__(16) short p_lds[16][40];
  int lo = t0 - (CTX - 1); if (lo < 0) lo = 0;
  int kt_lo = lo & ~31;
  int kt_hi = (t0 + 15) & ~31;
  for (int kt = kt_lo; kt <= kt_hi; kt += 32) {
    f32x4 s2[2];
#pragma unroll
    for (int hh = 0; hh < 2; hh++) {
      int key = kt + hh * 16 + lr;
      int kload = key < TT ? key : TT - 1;
      f32x4 sa = {};
#pragma unroll
      for (int d2 = 0; d2 < 2; d2++) {
        s16x8 kf = *reinterpret_cast<const s16x8*>(Kp + kload * HD + d2 * 32 + lg * 8);
        sa = __builtin_amdgcn_mfma_f32_16x16x32_bf16(qf[d2], kf, sa, 0, 0, 0);
      }
      s2[hh] = sa;
    }
#pragma unroll
    for (int r = 0; r < 4; r++) {
      int row = t0 + lg * 4 + r;
      float sv[2]; bool vd[2];
#pragma unroll
      for (int hh = 0; hh < 2; hh++) {
        int col = kt + hh * 16 + lr;
        int dl = row - col;
        vd[hh] = (dl >= 0) && (dl < CTX);
        sv[hh] = vd[hh] ? s2[hh][r] * 0.125f : NEG;
      }
      float mx = fmaxf(sv[0], sv[1]);
#pragma unroll
      for (int off = 1; off < 16; off <<= 1) mx = fmaxf(mx, __shfl_xor(mx, off, 16));
      float mnew = fmaxf(m_run[r], mx);
      float corr = __expf(m_run[r] - mnew);  // NEG-NEG=0 -> 1 (of/l are 0: ok); NEG-finite -> 0
      float psum = 0.0f;
#pragma unroll
      for (int hh = 0; hh < 2; hh++) {
        float p = vd[hh] ? __expf(sv[hh] - mnew) : 0.0f;
        p_lds[lg * 4 + r][hh * 16 + lr] = f2bf(p);
        psum += p;
      }
#pragma unroll
      for (int off = 1; off < 16; off <<= 1) psum += __shfl_xor(psum, off, 16);
      l_run[r] = l_run[r] * corr + psum;
      m_run[r] = mnew;
#pragma unroll
      for (int n = 0; n < 4; n++) of[n][r] *= corr;
    }
    __syncthreads();
    s16x8 pa = *reinterpret_cast<const s16x8*>(&p_lds[lr][lg * 8]);
#pragma unroll
    for (int n = 0; n < 4; n++) {
      s16x8 vf;
#pragma unroll
      for (int i = 0; i < 8; i++) {
        int k = kt + lg * 8 + i;
        int kl = k < TT ? k : TT - 1;
        vf[i] = Vp[kl * HD + n * 16 + lr];
      }
      of[n] = __builtin_amdgcn_mfma_f32_16x16x32_bf16(pa, vf, of[n], 0, 0, 0);
    }
    __syncthreads();
  }
#pragma unroll
  for (int r = 0; r < 4; r++) {
    float inv = 1.0f / l_run[r];
    int row = t0 + lg * 4 + r;
#pragma unroll
    for (int n = 0; n < 4; n++)
      Xout[(b * TT + row) * EMB + h * HD + n * 16 + lr] = f2bf(of[n][r] * inv);
  }
}

extern "C" void kernel_launch(void* const* d_in, const int* in_sizes, int n_in,
                              void* d_out, int out_size, void* d_ws, size_t ws_size,
                              hipStream_t stream) {
  const float* query = (const float*)d_in[0];
  const float* w_in  = (const float*)d_in[1];
  const float* w_out = (const float*)d_in[2];
  char* ws = (char*)d_ws;
  // layout (bytes):
  short* qbf   = (short*)(ws + 0);          //  8388608  query bf16 [4096][1024]
  short* wibf  = (short*)(ws + 8388608);    //  6291456  in_proj bf16 [3072][1024]
  short* wobf  = (short*)(ws + 14680064);   //  2097152  out_proj bf16 [1024][1024]
  short* proj  = (short*)(ws + 16777216);   // 25165824  qkv proj bf16 [4096][3072]
  short* attnx = (short*)(ws + 16777216);   // alias: proj is dead after rope
  short* Qb    = (short*)(ws + 41943040);   //  8388608  [B][H][T][D]
  short* Kb    = (short*)(ws + 50331648);   //  8388608
  short* Vb    = (short*)(ws + 58720256);   //  8388608  (end 67108864 = 64 MB)

  cvt_bf16x4<<<4096, 256, 0, stream>>>(query, qbf, 1048576);
  cvt_bf16x4<<<3072, 256, 0, stream>>>(w_in, wibf, 786432);
  cvt_bf16x4<<<1024, 256, 0, stream>>>(w_out, wobf, 262144);
  gemm_bt<true><<<dim3(24, 32), 256, 0, stream>>>(qbf, wibf, (void*)proj, 3072, 1024);
  rope_kernel<<<8192, 256, 0, stream>>>(proj, Qb, Kb, Vb);
  attn_kernel<<<dim3(128, 32), 64, 0, stream>>>(Qb, Kb, Vb, attnx);
  gemm_bt<false><<<dim3(8, 32), 256, 0, stream>>>(attnx, wobf, d_out, 1024, 1024);
}

// Round 2
// 135.145 us; speedup vs baseline: 1.4653x; 1.4653x over previous
//
#include <hip/hip_runtime.h>

#define TT 2048
#define EMB 1024
#define NH 16
#define HD 64
#define CTX 250

typedef __attribute__((ext_vector_type(4))) float f32x4;
typedef __attribute__((ext_vector_type(8))) short s16x8;
typedef __attribute__((ext_vector_type(4))) short s16x4;

#define LDS_PTR(p) ((__attribute__((address_space(3))) void*)(p))
#define GLB_PTR(p) ((const __attribute__((address_space(1))) void*)(p))

__device__ __forceinline__ short f2bf(float f) {
  union { float f; unsigned u; } v; v.f = f;
  unsigned r = v.u + 0x7fffu + ((v.u >> 16) & 1u);
  return (short)(r >> 16);
}
__device__ __forceinline__ float bf2f(unsigned short u) {
  union { unsigned u; float f; } v; v.u = ((unsigned)u) << 16;
  return v.f;
}

__global__ void cvt_bf16x4(const float* __restrict__ in, short* __restrict__ out, int n4) {
  int i = blockIdx.x * blockDim.x + threadIdx.x;
  if (i >= n4) return;
  float4 v = reinterpret_cast<const float4*>(in)[i];
  s16x4 o; o[0] = f2bf(v.x); o[1] = f2bf(v.y); o[2] = f2bf(v.z); o[3] = f2bf(v.w);
  *reinterpret_cast<s16x4*>(out + i * 4) = o;
}

// C[M][N] = A[M][K] * W[N][K]^T  (bf16, MFMA 16x16x32, f32 accum)
// m97 structure: LDS staging via global_load_lds width-16, BK=32, 4 waves,
// 2-barrier K-loop. BM in {128, 64}; BN=128. Wave (wid>>1, wid&1) owns
// (BM/2)x64 of the output tile.
template<int BM, bool BF16OUT>
__global__ __launch_bounds__(256) void gemm_lds(const short* __restrict__ A,
                                                const short* __restrict__ W,
                                                void* __restrict__ Cv, int N, int K) {
  constexpr int BN = 128;
  constexpr int BK = 32;
  constexpr int MFR = BM / 32;  // 16-row A-frags per wave
  __shared__ __align__(16) short As[BM * BK];
  __shared__ __align__(16) short Bs[BN * BK];
  const int lane = threadIdx.x & 63;
  const int wid  = threadIdx.x >> 6;
  const int lr = lane & 15, lg = lane >> 4;
  const int rblk = blockIdx.y * BM;
  const int cblk = blockIdx.x * BN;
  const int wrow = (wid >> 1) * (BM / 2);
  const int wcol = (wid & 1) * 64;
  // staging geometry: one 1024B wave-instr covers 16 rows of [*][32] bf16
  const int srow = lane >> 2;
  const int scol = (lane & 3) * 8;
  f32x4 acc[MFR][4] = {};

  for (int kk = 0; kk < K; kk += BK) {
    // ---- stage A (BM/64 instrs/wave) + B (2 instrs/wave) ----
#pragma unroll
    for (int j = 0; j < BM / 64; j++) {
      int seg = wid * (BM / 64) + j;
      const short* g = A + (size_t)(rblk + seg * 16 + srow) * K + kk + scol;
      __builtin_amdgcn_global_load_lds(GLB_PTR(g), LDS_PTR(&As[seg * 512]), 16, 0, 0);
    }
#pragma unroll
    for (int j = 0; j < 2; j++) {
      int seg = wid * 2 + j;
      const short* g = W + (size_t)(cblk + seg * 16 + srow) * K + kk + scol;
      __builtin_amdgcn_global_load_lds(GLB_PTR(g), LDS_PTR(&Bs[seg * 512]), 16, 0, 0);
    }
    __syncthreads();  // drains vmcnt(0): staged tile visible to all waves
    // ---- compute ----
    s16x8 af[MFR], bfr[4];
#pragma unroll
    for (int m = 0; m < MFR; m++)
      af[m] = *reinterpret_cast<const s16x8*>(&As[(wrow + m * 16 + lr) * BK + lg * 8]);
#pragma unroll
    for (int n = 0; n < 4; n++)
      bfr[n] = *reinterpret_cast<const s16x8*>(&Bs[(wcol + n * 16 + lr) * BK + lg * 8]);
#pragma unroll
    for (int m = 0; m < MFR; m++)
#pragma unroll
      for (int n = 0; n < 4; n++)
        acc[m][n] = __builtin_amdgcn_mfma_f32_16x16x32_bf16(af[m], bfr[n], acc[m][n], 0, 0, 0);
    __syncthreads();  // LDS consumed; next iter may overwrite
  }
#pragma unroll
  for (int m = 0; m < MFR; m++)
#pragma unroll
    for (int n = 0; n < 4; n++)
#pragma unroll
      for (int r = 0; r < 4; r++) {
        int row = rblk + wrow + m * 16 + lg * 4 + r;
        int col = cblk + wcol + n * 16 + lr;
        float val = acc[m][n][r];
        if constexpr (BF16OUT) ((short*)Cv)[(size_t)row * N + col] = f2bf(val);
        else                   ((float*)Cv)[(size_t)row * N + col] = val;
      }
}

// proj (bf16, [B][T][3][H][D]) -> RoPE -> Qb/Kb/Vb (bf16, [B][H][T][D])
__global__ void rope_kernel(const short* __restrict__ proj, short* __restrict__ Qb,
                            short* __restrict__ Kb, short* __restrict__ Vb) {
  int idx = blockIdx.x * blockDim.x + threadIdx.x;  // B*H*T*32 = 2097152
  int i = idx & 31;
  int t = (idx >> 5) & (TT - 1);
  int h = (idx >> 16) & (NH - 1);
  int b = idx >> 20;
  int pbase = (b * TT + t) * 3 * EMB + h * HD + 2 * i;
  unsigned q01 = *reinterpret_cast<const unsigned*>(proj + pbase);
  unsigned k01 = *reinterpret_cast<const unsigned*>(proj + pbase + EMB);
  unsigned v01 = *reinterpret_cast<const unsigned*>(proj + pbase + 2 * EMB);
  float qa = bf2f((unsigned short)(q01 & 0xffff)), qb_ = bf2f((unsigned short)(q01 >> 16));
  float ka = bf2f((unsigned short)(k01 & 0xffff)), kb_ = bf2f((unsigned short)(k01 >> 16));
  float freq = __expf(-(float)i * 0.2878231366f);  // ln(10000)/32
  float ang = (float)t * freq;
  float s, c;
  sincosf(ang, &s, &c);
  int obase = ((b * NH + h) * TT + t) * HD + 2 * i;
  unsigned qo = ((unsigned)(unsigned short)f2bf(qa * s + qb_ * c) << 16) |
                (unsigned short)f2bf(qa * c - qb_ * s);
  unsigned ko = ((unsigned)(unsigned short)f2bf(ka * s + kb_ * c) << 16) |
                (unsigned short)f2bf(ka * c - kb_ * s);
  *reinterpret_cast<unsigned*>(Qb + obase) = qo;
  *reinterpret_cast<unsigned*>(Kb + obase) = ko;
  *reinterpret_cast<unsigned*>(Vb + obase) = v01;
}

// one wave per (bh, 16-query-row tile). Flash-style over 32-key tiles.
__global__ __launch_bounds__(64) void attn_kernel(const short* __restrict__ Qb,
                                                  const short* __restrict__ Kb,
                                                  const short* __restrict__ Vb,
                                                  short* __restrict__ Xout) {
  const float NEG = -3.0e38f;
  int lane = threadIdx.x;
  int lr = lane & 15, lg = lane >> 4;
  int t0 = blockIdx.x * 16;
  int bh = blockIdx.y;
  int b = bh >> 4, h = bh & 15;
  const short* Qp = Qb + bh * TT * HD;
  const short* Kp = Kb + bh * TT * HD;
  const short* Vp = Vb + bh * TT * HD;
  s16x8 qf[2];
#pragma unroll
  for (int d2 = 0; d2 < 2; d2++)
    qf[d2] = *reinterpret_cast<const s16x8*>(Qp + (t0 + lr) * HD + d2 * 32 + lg * 8);
  f32x4 of[4] = {};
  float m_run[4], l_run[4];
#pragma unroll
  for (int r = 0; r < 4; r++) { m_run[r] = NEG; l_run[r] = 0.0f; }
  __shared__ __align__(16) short p_lds[16][40];
  int lo = t0 - (CTX - 1); if (lo < 0) lo = 0;
  int kt_lo = lo & ~31;
  int kt_hi = (t0 + 15) & ~31;
  for (int kt = kt_lo; kt <= kt_hi; kt += 32) {
    f32x4 s2[2];
#pragma unroll
    for (int hh = 0; hh < 2; hh++) {
      int key = kt + hh * 16 + lr;
      int kload = key < TT ? key : TT - 1;
      f32x4 sa = {};
#pragma unroll
      for (int d2 = 0; d2 < 2; d2++) {
        s16x8 kf = *reinterpret_cast<const s16x8*>(Kp + kload * HD + d2 * 32 + lg * 8);
        sa = __builtin_amdgcn_mfma_f32_16x16x32_bf16(qf[d2], kf, sa, 0, 0, 0);
      }
      s2[hh] = sa;
    }
#pragma unroll
    for (int r = 0; r < 4; r++) {
      int row = t0 + lg * 4 + r;
      float sv[2]; bool vd[2];
#pragma unroll
      for (int hh = 0; hh < 2; hh++) {
        int col = kt + hh * 16 + lr;
        int dl = row - col;
        vd[hh] = (dl >= 0) && (dl < CTX);
        sv[hh] = vd[hh] ? s2[hh][r] * 0.125f : NEG;
      }
      float mx = fmaxf(sv[0], sv[1]);
#pragma unroll
      for (int off = 1; off < 16; off <<= 1) mx = fmaxf(mx, __shfl_xor(mx, off, 16));
      float mnew = fmaxf(m_run[r], mx);
      float corr = __expf(m_run[r] - mnew);
      float psum = 0.0f;
#pragma unroll
      for (int hh = 0; hh < 2; hh++) {
        float p = vd[hh] ? __expf(sv[hh] - mnew) : 0.0f;
        p_lds[lg * 4 + r][hh * 16 + lr] = f2bf(p);
        psum += p;
      }
#pragma unroll
      for (int off = 1; off < 16; off <<= 1) psum += __shfl_xor(psum, off, 16);
      l_run[r] = l_run[r] * corr + psum;
      m_run[r] = mnew;
#pragma unroll
      for (int n = 0; n < 4; n++) of[n][r] *= corr;
    }
    __syncthreads();
    s16x8 pa = *reinterpret_cast<const s16x8*>(&p_lds[lr][lg * 8]);
#pragma unroll
    for (int n = 0; n < 4; n++) {
      s16x8 vf;
#pragma unroll
      for (int i = 0; i < 8; i++) {
        int k = kt + lg * 8 + i;
        int kl = k < TT ? k : TT - 1;
        vf[i] = Vp[kl * HD + n * 16 + lr];
      }
      of[n] = __builtin_amdgcn_mfma_f32_16x16x32_bf16(pa, vf, of[n], 0, 0, 0);
    }
    __syncthreads();
  }
#pragma unroll
  for (int r = 0; r < 4; r++) {
    float inv = 1.0f / l_run[r];
    int row = t0 + lg * 4 + r;
#pragma unroll
    for (int n = 0; n < 4; n++)
      Xout[(b * TT + row) * EMB + h * HD + n * 16 + lr] = f2bf(of[n][r] * inv);
  }
}

extern "C" void kernel_launch(void* const* d_in, const int* in_sizes, int n_in,
                              void* d_out, int out_size, void* d_ws, size_t ws_size,
                              hipStream_t stream) {
  const float* query = (const float*)d_in[0];
  const float* w_in  = (const float*)d_in[1];
  const float* w_out = (const float*)d_in[2];
  char* ws = (char*)d_ws;
  short* qbf   = (short*)(ws + 0);          //  8388608  query bf16 [4096][1024]
  short* wibf  = (short*)(ws + 8388608);    //  6291456  in_proj bf16 [3072][1024]
  short* wobf  = (short*)(ws + 14680064);   //  2097152  out_proj bf16 [1024][1024]
  short* proj  = (short*)(ws + 16777216);   // 25165824  qkv proj bf16 [4096][3072]
  short* attnx = (short*)(ws + 16777216);   // alias: proj is dead after rope
  short* Qb    = (short*)(ws + 41943040);   //  8388608  [B][H][T][D]
  short* Kb    = (short*)(ws + 50331648);   //  8388608
  short* Vb    = (short*)(ws + 58720256);   //  8388608  (end 67108864 = 64 MB)

  cvt_bf16x4<<<4096, 256, 0, stream>>>(query, qbf, 1048576);
  cvt_bf16x4<<<3072, 256, 0, stream>>>(w_in, wibf, 786432);
  cvt_bf16x4<<<1024, 256, 0, stream>>>(w_out, wobf, 262144);
  gemm_lds<128, true><<<dim3(24, 32), 256, 0, stream>>>(qbf, wibf, (void*)proj, 3072, 1024);
  rope_kernel<<<8192, 256, 0, stream>>>(proj, Qb, Kb, Vb);
  attn_kernel<<<dim3(128, 32), 64, 0, stream>>>(Qb, Kb, Vb, attnx);
  gemm_lds<64, false><<<dim3(8, 64), 256, 0, stream>>>(attnx, wobf, d_out, 1024, 1024);
}